// Round 24
// baseline (381.795 us; speedup 1.0000x reference)
//
#include <hip/hip_runtime.h>
#include <hip/hip_bf16.h>

// InstanSeg v24 = v21 scheduling x v8 compute (32 px per wave-candidate).
// R23 falsified the parked-AGPR model: v23's LDS-W2 at VGPR 116 was only
// 12% slower -> W2 is RELOADED per candidate in every variant (per-candidate
// ~2750 cyc vs ~550 modeled). Lever: amortize the reload over 2x pixels.
// v8 proved 32px costs ~1.19x per candidate with 0.5x candidates (net 0.6x)
// but lost to scheduling; v21's one-wave blocks + center-out + setprio fix
// that. 4608 one-wave blocks, exact ballot lists, D inline, b2pk epilogue.

#define HH    384
#define WW    384
#define NE    32
#define NK    256
#define HALF  64
#define HWSZ  (HH * WW)
#define EPSV  1e-6f
#define CAPX  192     // per-list candidate cap

typedef _Float16 half8 __attribute__((ext_vector_type(8)));
typedef _Float16 half2v __attribute__((ext_vector_type(2)));
typedef float floatx4 __attribute__((ext_vector_type(4)));

#define MFMA16(a, b, c) __builtin_amdgcn_mfma_f32_16x16x32_f16((a), (b), (c), 0, 0, 0)

__device__ __forceinline__ half2v pk_f16(float a, float b) {
    return __builtin_bit_cast(half2v, __builtin_amdgcn_cvt_pkrtz(a, b));
}

__device__ __forceinline__ int row_order(int ri) {
    return (ri & 1) ? (191 - (ri >> 1)) : (192 + (ri >> 1));
}

// ---- ws layout (float-element offsets) ----
#define WS_DIST   0            // 4,194,304 f32 (16 MB)
#define WS_MSYM   4194304      // 65,536 f32
#define WS_W2F    4259840      // 16,384 f16 = 8,192 f32
#define WS_D      4268032      // 32,768 f16 = 16,384 f32
#define WS_CENTER 4284416      // 256 f32
#define WS_G      5026560      // 18,874,368 f16 = 9,437,184 f32

// ---------------------------------------------------------------- prep ----
__global__ void prep_kernel(const float* __restrict__ M, const float* __restrict__ W1,
                            const float* __restrict__ W2, const float* __restrict__ c,
                            const float* __restrict__ b1,
                            float* __restrict__ Msym, _Float16* __restrict__ W2f,
                            _Float16* __restrict__ D) {
    int idx = blockIdx.x * 256 + threadIdx.x;
    {   // Msym
        int i = idx >> 8, j = idx & 255;
        Msym[idx] = (i == j) ? 1.0f : 0.5f * (M[i * NK + j] + M[j * NK + i]);
    }
    if (idx < 2048) {   // W2f B-frags: lane l elem j = W2[32s+8(l>>4)+j][16nt+(l&15)]
        int l = idx & 63;
        int col = ((idx >> 8) << 4) + (l & 15);
        int kb = ((idx >> 6) & 3) * 32 + 8 * (l >> 4);
        #pragma unroll
        for (int j = 0; j < 8; ++j)
            W2f[idx * 8 + j] = (_Float16)W2[(kb + j) * 128 + col];
    }
    if (idx < 32768) {  // D[k][h] = W1^T c_k - b1
        int k = idx >> 7, h = idx & 127;
        float s = -b1[h];
        #pragma unroll 8
        for (int e = 0; e < NE; ++e) s = fmaf(c[k * NE + e], W1[e * 128 + h], s);
        D[idx] = (_Float16)s;
    }
}

// --------------------------------------------------------------- gfeat ----
__global__ __launch_bounds__(256)
void gfeat_kernel(const float* __restrict__ x, const float* __restrict__ sigma,
                  const float* __restrict__ W1, _Float16* __restrict__ G) {
    int px = blockIdx.x * 256 + threadIdx.x;
    float f[34];
    #pragma unroll
    for (int e = 0; e < NE; ++e) f[e] = x[e * HWSZ + px];
    f[32] = sigma[px];
    f[33] = sigma[HWSZ + px];
    _Float16* gp = G + (size_t)px * 128;
    #pragma unroll 1
    for (int h0 = 0; h0 < 128; h0 += 8) {
        half8 hv;
        #pragma unroll
        for (int j = 0; j < 8; ++j) {
            float z = 0.0f;
            const float* w1 = W1 + (h0 + j);
            #pragma unroll
            for (int e = 0; e < 34; ++e) z = fmaf(f[e], w1[e * 128], z);
            hv[j] = (_Float16)z;
        }
        *(half8*)(gp + h0) = hv;
    }
}

// -------------------------------------------------------------- center2 ---
__global__ __launch_bounds__(128)
void center2_kernel(const _Float16* __restrict__ G, const _Float16* __restrict__ D,
                    const float* __restrict__ W2, const float* __restrict__ b2,
                    const float* __restrict__ W3, const float* __restrict__ b3,
                    const int* __restrict__ cent, float* __restrict__ center) {
    __shared__ float h1s[128];
    __shared__ float red[2];
    int k = blockIdx.x, j = threadIdx.x;
    int cy0 = cent[2 * k], cx0 = cent[2 * k + 1];
    const _Float16* g = G + ((size_t)cy0 * WW + cx0) * 128;
    h1s[j] = fmaxf((float)g[j] - (float)D[k * 128 + j], 0.0f);
    __syncthreads();
    float acc = 0.0f;
    #pragma unroll 8
    for (int i = 0; i < 128; ++i) acc = fmaf(h1s[i], W2[i * 128 + j], acc);
    float p = fmaxf(acc + b2[j], 0.0f) * W3[j];
    #pragma unroll
    for (int m = 1; m < 64; m <<= 1) p += __shfl_xor(p, m, 64);
    if ((j & 63) == 0) red[j >> 6] = p;
    __syncthreads();
    if (j == 0) center[k] = red[0] + red[1] + b3[0];
}

// ----------------------------------------------------------------- pix ----
// 4608 one-wave blocks (64 thr): block = (row, 32-px strip). Exact ballot
// list; per candidate: 64 MFMA covering 32 px (each W2 fragment used 2x).
__global__ __launch_bounds__(64)
void pix_kernel(const _Float16* __restrict__ G, const _Float16* __restrict__ D,
                const _Float16* __restrict__ W2f, const int* __restrict__ cent,
                const float* __restrict__ b2, const float* __restrict__ W3,
                const float* __restrict__ b3, const float* __restrict__ center,
                float* __restrict__ dist) {
    __shared__ int   sjw[CAPX];
    __shared__ float sctr[CAPX];

    const int l   = threadIdx.x;
    const int lg  = l >> 4;
    const int xi  = l & 15;

    const int bid = blockIdx.x;
    const int r   = row_order(bid / 12);
    const int wx0 = (bid % 12) * 32;             // wave's 32-px x-origin

    // ---- exact candidate list for this 32-px span (ballot-prefix) ----
    int nc;
    {
        int base = 0;
        const int2* c2 = (const int2*)cent;
        #pragma unroll
        for (int cch = 0; cch < 4; ++cch) {
            int j = cch * 64 + l;
            int2 cc = c2[j];
            int ty = min(max(cc.x, HALF), HH - HALF) - HALF;
            int tx = min(max(cc.y, HALF), WW - HALF) - HALF;
            bool f = (r >= ty) && (r < ty + 128) &&
                     (tx <= wx0 + 31) && (tx + 127 >= wx0);
            unsigned long long m = __ballot(f);
            int pos = base + __popcll(m & ((1ull << l) - 1ull));
            if (f && pos < CAPX) {
                sjw[pos]  = (j << 20) | (ty << 10) | tx;
                sctr[pos] = center[j];
            }
            base += __popcll(m);
        }
        nc = min(base, CAPX);
    }

    // ---- loop-invariant registers ----
    half8 B2w[8][4];
    const half8* W2f8 = (const half8*)W2f;
    #pragma unroll
    for (int n = 0; n < 8; ++n)
        #pragma unroll
        for (int s = 0; s < 4; ++s) B2w[n][s] = W2f8[(n * 4 + s) * 64 + l];

    half2v b2pk[8][2], w3pk[8][2];
    #pragma unroll
    for (int n = 0; n < 8; ++n)
        #pragma unroll
        for (int q = 0; q < 2; ++q) {
            int o = 16 * n + 4 * lg + 2 * q;
            b2pk[n][q] = half2v{(_Float16)b2[o], (_Float16)b2[o + 1]};
            w3pk[n][q] = half2v{(_Float16)W3[o], (_Float16)W3[o + 1]};
        }
    const float b3s = b3[0];

    // G fragments for the wave's 32 px (two 16-px groups), loaded ONCE
    half8 gA0[4], gA1[4];
    {
        const char* Gb0 = (const char*)G + ((size_t)r * WW + wx0 + xi) * 256 + lg * 16;
        const char* Gb1 = Gb0 + 16 * 256;
        #pragma unroll
        for (int s = 0; s < 4; ++s) {
            gA0[s] = *(const half8*)(Gb0 + s * 64);
            gA1[s] = *(const half8*)(Gb1 + s * 64);
        }
    }
    const half8 hz = half8{};

    // ---- candidate loop (D inline; 2 px-groups per W2 fragment) ----
    #pragma unroll 1
    for (int i = 0; i < nc; ++i) {
        int cp = sjw[i];
        float bc = sctr[i];
        int tx = cp & 1023, ty = (cp >> 10) & 1023, j = cp >> 20;

        const char* Dp = (const char*)D + j * 256 + lg * 16;
        half8 hin0[4], hin1[4];
        #pragma unroll
        for (int s = 0; s < 4; ++s) {
            half8 dv = *(const half8*)(Dp + s * 64);
            hin0[s] = __builtin_elementwise_max(gA0[s] - dv, hz);
            hin1[s] = __builtin_elementwise_max(gA1[s] - dv, hz);
        }

        float p0 = 0.0f, p1 = 0.0f;
        __builtin_amdgcn_s_setprio(1);
        #pragma unroll
        for (int n = 0; n < 8; ++n) {
            floatx4 a0 = floatx4{0.0f, 0.0f, 0.0f, 0.0f};
            floatx4 a1 = a0;
            #pragma unroll
            for (int s = 0; s < 4; ++s) {
                a0 = MFMA16(B2w[n][s], hin0[s], a0);
                a1 = MFMA16(B2w[n][s], hin1[s], a1);
            }
            half2v h00 = __builtin_elementwise_max(pk_f16(a0[0], a0[1]) + b2pk[n][0], half2v{});
            half2v h01 = __builtin_elementwise_max(pk_f16(a0[2], a0[3]) + b2pk[n][1], half2v{});
            half2v h10 = __builtin_elementwise_max(pk_f16(a1[0], a1[1]) + b2pk[n][0], half2v{});
            half2v h11 = __builtin_elementwise_max(pk_f16(a1[2], a1[3]) + b2pk[n][1], half2v{});
            p0 = __builtin_amdgcn_fdot2(h00, w3pk[n][0], p0, false);
            p0 = __builtin_amdgcn_fdot2(h01, w3pk[n][1], p0, false);
            p1 = __builtin_amdgcn_fdot2(h10, w3pk[n][0], p1, false);
            p1 = __builtin_amdgcn_fdot2(h11, w3pk[n][1], p1, false);
        }
        __builtin_amdgcn_s_setprio(0);
        p0 += __shfl_xor(p0, 16, 64);
        p0 += __shfl_xor(p0, 32, 64);
        p1 += __shfl_xor(p1, 16, 64);
        p1 += __shfl_xor(p1, 32, 64);

        if (lg < 2) {
            float pv = (lg == 0) ? p0 : p1;
            int px = wx0 + lg * 16 + xi;
            unsigned dx = (unsigned)(px - tx);
            if (dx < 128u) {
                float d = pv + b3s;
                float mm = fmaxf(fmaxf(d, bc), 0.0f);
                float lgv = mm + __logf(__expf(0.0f - mm) + __expf(d - mm) +
                                        __expf(bc - mm));
                dist[((size_t)j << 14) + ((r - ty) << 7) + (int)dx] = d + bc - lgv;
            }
        }
    }
}

// --------------------------------------------------------------- merge ----
// 2304 blocks of 256. dl staged as f16 (24KB) + per-t (m,tx) pairs in LDS.
__global__ __launch_bounds__(256)
void merge_kernel(const float* __restrict__ dist, const int* __restrict__ cent,
                  const float* __restrict__ Msym, float* __restrict__ out) {
    __shared__ _Float16 dl[CAPX][64];    // 24 KB
    __shared__ int   sjw[CAPX];
    __shared__ int2  mpk[4][CAPX];       // 6 KB {m bits, tx}
    __shared__ int   scnt;

    const int tid = threadIdx.x;
    const int l   = tid & 63;
    const int wv  = tid >> 6;
    const int r   = row_order(blockIdx.x / 6);
    const int xt  = blockIdx.x % 6;
    const int px  = xt * 64 + l;

    if (wv == 0) {
        int base = 0;
        const int2* c2 = (const int2*)cent;
        #pragma unroll
        for (int cch = 0; cch < 4; ++cch) {
            int j = cch * 64 + l;
            int2 cc = c2[j];
            int ty = min(max(cc.x, HALF), HH - HALF) - HALF;
            int tx = min(max(cc.y, HALF), WW - HALF) - HALF;
            bool f = (r >= ty) && (r < ty + 128) &&
                     (tx <= xt * 64 + 63) && (tx + 127 >= xt * 64);
            unsigned long long m = __ballot(f);
            int pos = base + __popcll(m & ((1ull << l) - 1ull));
            if (f && pos < CAPX) sjw[pos] = (j << 20) | (ty << 10) | tx;
            base += __popcll(m);
        }
        if (l == 0) scnt = min(base, CAPX);
    }
    __syncthreads();
    const int nc = scnt;

    #pragma unroll 1
    for (int j = wv; j < nc; j += 4) {
        int cp = sjw[j];
        int tx = cp & 1023, ty = (cp >> 10) & 1023, jj = cp >> 20;
        unsigned dx = (unsigned)(px - tx);
        float v = 0.0f;
        if (dx < 128u) v = dist[((size_t)jj << 14) + ((r - ty) << 7) + (int)dx];
        dl[j][l] = (_Float16)v;
    }
    __syncthreads();

    #pragma unroll 1
    for (int t = wv; t < nc; t += 4) {
        int cpt = sjw[t];
        int kt = cpt >> 20;
        const float* mrow = Msym + kt * NK;
        #pragma unroll
        for (int cch = 0; cch < 3; ++cch) {
            int j2 = cch * 64 + l;
            if (j2 < nc) {
                int cj = sjw[j2];
                mpk[wv][j2] = int2{__builtin_bit_cast(int, mrow[cj >> 20]),
                                   cj & 1023};
            }
        }
        float num = 0.0f, den = 0.0f;
        #pragma unroll 4
        for (int j = 0; j < nc; ++j) {
            int2 mp = mpk[wv][j];
            float m = __builtin_bit_cast(float, mp.x);
            num = fmaf(m, (float)dl[j][l], num);
            unsigned dxj = (unsigned)(px - mp.y);
            den += (dxj < 128u) ? m : 0.0f;
        }
        unsigned dxk = (unsigned)(px - (cpt & 1023));
        if (dxk < 128u)
            out[((size_t)kt << 14) + ((r - ((cpt >> 10) & 1023)) << 7) + (int)dxk] =
                num / fmaxf(den, EPSV);
    }
}

// -------------------------------------------------------------- launch ----
extern "C" void kernel_launch(void* const* d_in, const int* in_sizes, int n_in,
                              void* d_out, int out_size, void* d_ws, size_t ws_size,
                              hipStream_t stream) {
    const float* x     = (const float*)d_in[0];
    const float* sigma = (const float*)d_in[1];
    const float* c     = (const float*)d_in[2];
    const int*   cent  = (const int*)d_in[3];
    const float* M     = (const float*)d_in[4];
    const float* W1    = (const float*)d_in[5];
    const float* b1    = (const float*)d_in[6];
    const float* W2    = (const float*)d_in[7];
    const float* b2    = (const float*)d_in[8];
    const float* W3    = (const float*)d_in[9];
    const float* b3    = (const float*)d_in[10];
    float* out = (float*)d_out;

    float* ws       = (float*)d_ws;
    float* dist     = ws + WS_DIST;
    float* Msym     = ws + WS_MSYM;
    _Float16* W2f   = (_Float16*)(ws + WS_W2F);
    _Float16* D     = (_Float16*)(ws + WS_D);
    float* center   = ws + WS_CENTER;
    _Float16* G     = (_Float16*)(ws + WS_G);

    prep_kernel<<<256, 256, 0, stream>>>(M, W1, W2, c, b1, Msym, W2f, D);
    gfeat_kernel<<<576, 256, 0, stream>>>(x, sigma, W1, G);
    center2_kernel<<<256, 128, 0, stream>>>(G, D, W2, b2, W3, b3, cent, center);
    pix_kernel<<<4608, 64, 0, stream>>>(G, D, W2f, cent, b2, W3, b3, center, dist);
    merge_kernel<<<2304, 256, 0, stream>>>(dist, cent, Msym, out);
}

// Round 25
// 279.106 us; speedup vs baseline: 1.3679x; 1.3679x over previous
//
#include <hip/hip_runtime.h>
#include <hip/hip_bf16.h>

// InstanSeg v25 = v21 (302.6us best: one-wave pix blocks, W2-in-regs,
// center-out, setprio) + the last zero-register graft: transform moved
// from pix's masked epilogue (3 exp + log on TRANS pipe per candidate)
// to merge's staging pass (v17-proven code; no atomics needed since each
// v21 wave produces complete d values). pix stores raw p; sctr deleted.
// R24 closed the 32px path (VGPR 132+128parked > 256 bucket -> occ 9.9%).

#define HH    384
#define WW    384
#define NE    32
#define NK    256
#define HALF  64
#define HWSZ  (HH * WW)
#define EPSV  1e-6f
#define CAPX  192     // per-list candidate cap

typedef _Float16 half8 __attribute__((ext_vector_type(8)));
typedef _Float16 half2v __attribute__((ext_vector_type(2)));
typedef float floatx4 __attribute__((ext_vector_type(4)));

#define MFMA16(a, b, c) __builtin_amdgcn_mfma_f32_16x16x32_f16((a), (b), (c), 0, 0, 0)

__device__ __forceinline__ half2v pk_f16(float a, float b) {
    return __builtin_bit_cast(half2v, __builtin_amdgcn_cvt_pkrtz(a, b));
}

__device__ __forceinline__ int row_order(int ri) {
    return (ri & 1) ? (191 - (ri >> 1)) : (192 + (ri >> 1));
}

// ---- ws layout (float-element offsets) ----
#define WS_DIST   0            // 4,194,304 f32 (16 MB)
#define WS_MSYM   4194304      // 65,536 f32
#define WS_W2F    4259840      // 16,384 f16 = 8,192 f32
#define WS_D      4268032      // 32,768 f16 = 16,384 f32
#define WS_CENTER 4284416      // 256 f32
#define WS_G      5026560      // 18,874,368 f16 = 9,437,184 f32

// ---------------------------------------------------------------- prep ----
__global__ void prep_kernel(const float* __restrict__ M, const float* __restrict__ W1,
                            const float* __restrict__ W2, const float* __restrict__ c,
                            const float* __restrict__ b1,
                            float* __restrict__ Msym, _Float16* __restrict__ W2f,
                            _Float16* __restrict__ D) {
    int idx = blockIdx.x * 256 + threadIdx.x;
    {   // Msym
        int i = idx >> 8, j = idx & 255;
        Msym[idx] = (i == j) ? 1.0f : 0.5f * (M[i * NK + j] + M[j * NK + i]);
    }
    if (idx < 2048) {   // W2f B-frags: lane l elem j = W2[32s+8(l>>4)+j][16nt+(l&15)]
        int l = idx & 63;
        int col = ((idx >> 8) << 4) + (l & 15);
        int kb = ((idx >> 6) & 3) * 32 + 8 * (l >> 4);
        #pragma unroll
        for (int j = 0; j < 8; ++j)
            W2f[idx * 8 + j] = (_Float16)W2[(kb + j) * 128 + col];
    }
    if (idx < 32768) {  // D[k][h] = W1^T c_k - b1
        int k = idx >> 7, h = idx & 127;
        float s = -b1[h];
        #pragma unroll 8
        for (int e = 0; e < NE; ++e) s = fmaf(c[k * NE + e], W1[e * 128 + h], s);
        D[idx] = (_Float16)s;
    }
}

// --------------------------------------------------------------- gfeat ----
__global__ __launch_bounds__(256)
void gfeat_kernel(const float* __restrict__ x, const float* __restrict__ sigma,
                  const float* __restrict__ W1, _Float16* __restrict__ G) {
    int px = blockIdx.x * 256 + threadIdx.x;
    float f[34];
    #pragma unroll
    for (int e = 0; e < NE; ++e) f[e] = x[e * HWSZ + px];
    f[32] = sigma[px];
    f[33] = sigma[HWSZ + px];
    _Float16* gp = G + (size_t)px * 128;
    #pragma unroll 1
    for (int h0 = 0; h0 < 128; h0 += 8) {
        half8 hv;
        #pragma unroll
        for (int j = 0; j < 8; ++j) {
            float z = 0.0f;
            const float* w1 = W1 + (h0 + j);
            #pragma unroll
            for (int e = 0; e < 34; ++e) z = fmaf(f[e], w1[e * 128], z);
            hv[j] = (_Float16)z;
        }
        *(half8*)(gp + h0) = hv;
    }
}

// -------------------------------------------------------------- center2 ---
__global__ __launch_bounds__(128)
void center2_kernel(const _Float16* __restrict__ G, const _Float16* __restrict__ D,
                    const float* __restrict__ W2, const float* __restrict__ b2,
                    const float* __restrict__ W3, const float* __restrict__ b3,
                    const int* __restrict__ cent, float* __restrict__ center) {
    __shared__ float h1s[128];
    __shared__ float red[2];
    int k = blockIdx.x, j = threadIdx.x;
    int cy0 = cent[2 * k], cx0 = cent[2 * k + 1];
    const _Float16* g = G + ((size_t)cy0 * WW + cx0) * 128;
    h1s[j] = fmaxf((float)g[j] - (float)D[k * 128 + j], 0.0f);
    __syncthreads();
    float acc = 0.0f;
    #pragma unroll 8
    for (int i = 0; i < 128; ++i) acc = fmaf(h1s[i], W2[i * 128 + j], acc);
    float p = fmaxf(acc + b2[j], 0.0f) * W3[j];
    #pragma unroll
    for (int m = 1; m < 64; m <<= 1) p += __shfl_xor(p, m, 64);
    if ((j & 63) == 0) red[j >> 6] = p;
    __syncthreads();
    if (j == 0) center[k] = red[0] + red[1] + b3[0];
}

// ----------------------------------------------------------------- pix ----
// 9216 one-wave blocks (64 thr): block = (row, 16-px strip). Exact ballot
// list; D inline; stores RAW p (transform + b3 applied in merge staging).
__global__ __launch_bounds__(64)
void pix_kernel(const _Float16* __restrict__ G, const _Float16* __restrict__ D,
                const _Float16* __restrict__ W2f, const int* __restrict__ cent,
                const float* __restrict__ b2, const float* __restrict__ W3,
                float* __restrict__ dist) {
    __shared__ int sjw[CAPX];

    const int l   = threadIdx.x;
    const int lg  = l >> 4;
    const int xi  = l & 15;

    const int bid = blockIdx.x;
    const int r   = row_order(bid / 24);
    const int wx0 = (bid % 24) * 16;             // wave's 16-px x-origin

    // ---- exact candidate list for this 16-px span (ballot-prefix) ----
    int nc;
    {
        int base = 0;
        const int2* c2 = (const int2*)cent;
        #pragma unroll
        for (int cch = 0; cch < 4; ++cch) {
            int j = cch * 64 + l;
            int2 cc = c2[j];
            int ty = min(max(cc.x, HALF), HH - HALF) - HALF;
            int tx = min(max(cc.y, HALF), WW - HALF) - HALF;
            bool f = (r >= ty) && (r < ty + 128) &&
                     (tx <= wx0 + 15) && (tx + 127 >= wx0);
            unsigned long long m = __ballot(f);
            int pos = base + __popcll(m & ((1ull << l) - 1ull));
            if (f && pos < CAPX) sjw[pos] = (j << 20) | (ty << 10) | tx;
            base += __popcll(m);
        }
        nc = min(base, CAPX);
    }

    // ---- loop-invariant registers (full W2 per wave) ----
    half8 B2w[8][4];
    const half8* W2f8 = (const half8*)W2f;
    #pragma unroll
    for (int n = 0; n < 8; ++n)
        #pragma unroll
        for (int s = 0; s < 4; ++s) B2w[n][s] = W2f8[(n * 4 + s) * 64 + l];

    float b2v[8][4];
    half2v w3pk[8][2];
    #pragma unroll
    for (int n = 0; n < 8; ++n) {
        #pragma unroll
        for (int q = 0; q < 4; ++q) b2v[n][q] = b2[16 * n + 4 * lg + q];
        #pragma unroll
        for (int q = 0; q < 2; ++q)
            w3pk[n][q] = half2v{(_Float16)W3[16 * n + 4 * lg + 2 * q],
                                (_Float16)W3[16 * n + 4 * lg + 2 * q + 1]};
    }

    // G fragments for this wave's 16 px (loaded ONCE)
    half8 gA[4];
    {
        const char* Gb = (const char*)G + ((size_t)r * WW + wx0 + xi) * 256 + lg * 16;
        #pragma unroll
        for (int s = 0; s < 4; ++s) gA[s] = *(const half8*)(Gb + s * 64);
    }
    const half8 hz = half8{};

    // ---- candidate loop (D loaded inline; raw store) ----
    #pragma unroll 1
    for (int i = 0; i < nc; ++i) {
        int cp = sjw[i];
        int tx = cp & 1023, ty = (cp >> 10) & 1023, j = cp >> 20;

        const char* Dp = (const char*)D + j * 256 + lg * 16;
        half8 hin[4];
        #pragma unroll
        for (int s = 0; s < 4; ++s) {
            half8 dv = *(const half8*)(Dp + s * 64);
            hin[s] = __builtin_elementwise_max(gA[s] - dv, hz);
        }

        float p = 0.0f;
        __builtin_amdgcn_s_setprio(1);
        #pragma unroll
        for (int n = 0; n < 8; ++n) {
            floatx4 acc = floatx4{b2v[n][0], b2v[n][1], b2v[n][2], b2v[n][3]};
            #pragma unroll
            for (int s = 0; s < 4; ++s)
                acc = MFMA16(B2w[n][s], hin[s], acc);       // D[row=h2, col=px]
            half2v h0 = __builtin_elementwise_max(pk_f16(acc[0], acc[1]), half2v{});
            half2v h1 = __builtin_elementwise_max(pk_f16(acc[2], acc[3]), half2v{});
            p = __builtin_amdgcn_fdot2(h0, w3pk[n][0], p, false);
            p = __builtin_amdgcn_fdot2(h1, w3pk[n][1], p, false);
        }
        __builtin_amdgcn_s_setprio(0);
        p += __shfl_xor(p, 16, 64);
        p += __shfl_xor(p, 32, 64);

        if (lg == 0) {
            int xcol = wx0 + xi;
            unsigned dx = (unsigned)(xcol - tx);
            if (dx < 128u)
                dist[((size_t)j << 14) + ((r - ty) << 7) + (int)dx] = p;
        }
    }
}

// --------------------------------------------------------------- merge ----
// 2304 blocks of 256. Staging applies +b3 and the center-transform
// (dist holds raw layer-3 sums). dl f16 + per-t (m,tx) pairs in LDS.
__global__ __launch_bounds__(256)
void merge_kernel(const float* __restrict__ dist, const int* __restrict__ cent,
                  const float* __restrict__ Msym, const float* __restrict__ center,
                  const float* __restrict__ b3, float* __restrict__ out) {
    __shared__ _Float16 dl[CAPX][64];    // 24 KB
    __shared__ int   sjw[CAPX];
    __shared__ int2  mpk[4][CAPX];       // 6 KB {m bits, tx}
    __shared__ int   scnt;

    const int tid = threadIdx.x;
    const int l   = tid & 63;
    const int wv  = tid >> 6;
    const int r   = row_order(blockIdx.x / 6);
    const int xt  = blockIdx.x % 6;
    const int px  = xt * 64 + l;
    const float b3s = b3[0];

    if (wv == 0) {
        int base = 0;
        const int2* c2 = (const int2*)cent;
        #pragma unroll
        for (int cch = 0; cch < 4; ++cch) {
            int j = cch * 64 + l;
            int2 cc = c2[j];
            int ty = min(max(cc.x, HALF), HH - HALF) - HALF;
            int tx = min(max(cc.y, HALF), WW - HALF) - HALF;
            bool f = (r >= ty) && (r < ty + 128) &&
                     (tx <= xt * 64 + 63) && (tx + 127 >= xt * 64);
            unsigned long long m = __ballot(f);
            int pos = base + __popcll(m & ((1ull << l) - 1ull));
            if (f && pos < CAPX) sjw[pos] = (j << 20) | (ty << 10) | tx;
            base += __popcll(m);
        }
        if (l == 0) scnt = min(base, CAPX);
    }
    __syncthreads();
    const int nc = scnt;

    // ---- stage dl[j][px]: raw sum -> +b3 -> center transform -> f16 ----
    #pragma unroll 1
    for (int j = wv; j < nc; j += 4) {
        int cp = sjw[j];
        int tx = cp & 1023, ty = (cp >> 10) & 1023, jj = cp >> 20;
        unsigned dx = (unsigned)(px - tx);
        float v = 0.0f;
        if (dx < 128u) {
            float d = dist[((size_t)jj << 14) + ((r - ty) << 7) + (int)dx] + b3s;
            float bc = center[jj];
            float mm = fmaxf(fmaxf(d, bc), 0.0f);
            float lgv = mm + __logf(__expf(0.0f - mm) + __expf(d - mm) +
                                    __expf(bc - mm));
            v = d + bc - lgv;
        }
        dl[j][l] = (_Float16)v;
    }
    __syncthreads();

    #pragma unroll 1
    for (int t = wv; t < nc; t += 4) {
        int cpt = sjw[t];
        int kt = cpt >> 20;
        const float* mrow = Msym + kt * NK;
        #pragma unroll
        for (int cch = 0; cch < 3; ++cch) {
            int j2 = cch * 64 + l;
            if (j2 < nc) {
                int cj = sjw[j2];
                mpk[wv][j2] = int2{__builtin_bit_cast(int, mrow[cj >> 20]),
                                   cj & 1023};
            }
        }
        float num = 0.0f, den = 0.0f;
        #pragma unroll 4
        for (int j = 0; j < nc; ++j) {
            int2 mp = mpk[wv][j];
            float m = __builtin_bit_cast(float, mp.x);
            num = fmaf(m, (float)dl[j][l], num);
            unsigned dxj = (unsigned)(px - mp.y);
            den += (dxj < 128u) ? m : 0.0f;
        }
        unsigned dxk = (unsigned)(px - (cpt & 1023));
        if (dxk < 128u)
            out[((size_t)kt << 14) + ((r - ((cpt >> 10) & 1023)) << 7) + (int)dxk] =
                num / fmaxf(den, EPSV);
    }
}

// -------------------------------------------------------------- launch ----
extern "C" void kernel_launch(void* const* d_in, const int* in_sizes, int n_in,
                              void* d_out, int out_size, void* d_ws, size_t ws_size,
                              hipStream_t stream) {
    const float* x     = (const float*)d_in[0];
    const float* sigma = (const float*)d_in[1];
    const float* c     = (const float*)d_in[2];
    const int*   cent  = (const int*)d_in[3];
    const float* M     = (const float*)d_in[4];
    const float* W1    = (const float*)d_in[5];
    const float* b1    = (const float*)d_in[6];
    const float* W2    = (const float*)d_in[7];
    const float* b2    = (const float*)d_in[8];
    const float* W3    = (const float*)d_in[9];
    const float* b3    = (const float*)d_in[10];
    float* out = (float*)d_out;

    float* ws       = (float*)d_ws;
    float* dist     = ws + WS_DIST;
    float* Msym     = ws + WS_MSYM;
    _Float16* W2f   = (_Float16*)(ws + WS_W2F);
    _Float16* D     = (_Float16*)(ws + WS_D);
    float* center   = ws + WS_CENTER;
    _Float16* G     = (_Float16*)(ws + WS_G);

    prep_kernel<<<256, 256, 0, stream>>>(M, W1, W2, c, b1, Msym, W2f, D);
    gfeat_kernel<<<576, 256, 0, stream>>>(x, sigma, W1, G);
    center2_kernel<<<256, 128, 0, stream>>>(G, D, W2, b2, W3, b3, cent, center);
    pix_kernel<<<9216, 64, 0, stream>>>(G, D, W2f, cent, b2, W3, dist);
    merge_kernel<<<2304, 256, 0, stream>>>(dist, cent, Msym, center, b3, out);
}

// Round 26
// 274.487 us; speedup vs baseline: 1.3909x; 1.0168x over previous
//
#include <hip/hip_runtime.h>
#include <hip/hip_bf16.h>

// InstanSeg v26 = v25 (279us best) + non-pix polish:
//  - merge: t-loop software-pipelined (t+4's Msym gathers issued before t's
//    inner loop; per-wave double-buffered m-values in LDS; static tx hoisted
//    to stx[] staged once). Same math, same order per output.
//  - prep+gfeat fused into one 832-block kernel (independent work, overlap).
// pix untouched (191us, structurally capped at 2 waves/SIMD per R8-R24).

#define HH    384
#define WW    384
#define NE    32
#define NK    256
#define HALF  64
#define HWSZ  (HH * WW)
#define EPSV  1e-6f
#define CAPX  192     // per-list candidate cap

typedef _Float16 half8 __attribute__((ext_vector_type(8)));
typedef _Float16 half2v __attribute__((ext_vector_type(2)));
typedef float floatx4 __attribute__((ext_vector_type(4)));

#define MFMA16(a, b, c) __builtin_amdgcn_mfma_f32_16x16x32_f16((a), (b), (c), 0, 0, 0)

__device__ __forceinline__ half2v pk_f16(float a, float b) {
    return __builtin_bit_cast(half2v, __builtin_amdgcn_cvt_pkrtz(a, b));
}

__device__ __forceinline__ int row_order(int ri) {
    return (ri & 1) ? (191 - (ri >> 1)) : (192 + (ri >> 1));
}

// ---- ws layout (float-element offsets) ----
#define WS_DIST   0            // 4,194,304 f32 (16 MB)
#define WS_MSYM   4194304      // 65,536 f32
#define WS_W2F    4259840      // 16,384 f16 = 8,192 f32
#define WS_D      4268032      // 32,768 f16 = 16,384 f32
#define WS_CENTER 4284416      // 256 f32
#define WS_G      5026560      // 18,874,368 f16 = 9,437,184 f32

// ---------------------------------------------------- prep + gfeat fused ----
// blocks 0..255: Msym/W2f/D prep. blocks 256..831: G = feat @ W1.
__global__ void prepg_kernel(const float* __restrict__ M, const float* __restrict__ W1,
                             const float* __restrict__ W2, const float* __restrict__ c,
                             const float* __restrict__ b1,
                             const float* __restrict__ x, const float* __restrict__ sigma,
                             float* __restrict__ Msym, _Float16* __restrict__ W2f,
                             _Float16* __restrict__ D, _Float16* __restrict__ G) {
    const int bid = blockIdx.x;
    const int tid = threadIdx.x;
    if (bid < 256) {
        int idx = bid * 256 + tid;
        {   // Msym
            int i = idx >> 8, j = idx & 255;
            Msym[idx] = (i == j) ? 1.0f : 0.5f * (M[i * NK + j] + M[j * NK + i]);
        }
        if (idx < 2048) {   // W2f B-frags: lane l elem j = W2[32s+8(l>>4)+j][16nt+(l&15)]
            int l = idx & 63;
            int col = ((idx >> 8) << 4) + (l & 15);
            int kb = ((idx >> 6) & 3) * 32 + 8 * (l >> 4);
            #pragma unroll
            for (int j = 0; j < 8; ++j)
                W2f[idx * 8 + j] = (_Float16)W2[(kb + j) * 128 + col];
        }
        if (idx < 32768) {  // D[k][h] = W1^T c_k - b1
            int k = idx >> 7, h = idx & 127;
            float s = -b1[h];
            #pragma unroll 8
            for (int e = 0; e < NE; ++e) s = fmaf(c[k * NE + e], W1[e * 128 + h], s);
            D[idx] = (_Float16)s;
        }
    } else {
        int px = (bid - 256) * 256 + tid;
        float f[34];
        #pragma unroll
        for (int e = 0; e < NE; ++e) f[e] = x[e * HWSZ + px];
        f[32] = sigma[px];
        f[33] = sigma[HWSZ + px];
        _Float16* gp = G + (size_t)px * 128;
        #pragma unroll 1
        for (int h0 = 0; h0 < 128; h0 += 8) {
            half8 hv;
            #pragma unroll
            for (int j = 0; j < 8; ++j) {
                float z = 0.0f;
                const float* w1 = W1 + (h0 + j);
                #pragma unroll
                for (int e = 0; e < 34; ++e) z = fmaf(f[e], w1[e * 128], z);
                hv[j] = (_Float16)z;
            }
            *(half8*)(gp + h0) = hv;
        }
    }
}

// -------------------------------------------------------------- center2 ---
__global__ __launch_bounds__(128)
void center2_kernel(const _Float16* __restrict__ G, const _Float16* __restrict__ D,
                    const float* __restrict__ W2, const float* __restrict__ b2,
                    const float* __restrict__ W3, const float* __restrict__ b3,
                    const int* __restrict__ cent, float* __restrict__ center) {
    __shared__ float h1s[128];
    __shared__ float red[2];
    int k = blockIdx.x, j = threadIdx.x;
    int cy0 = cent[2 * k], cx0 = cent[2 * k + 1];
    const _Float16* g = G + ((size_t)cy0 * WW + cx0) * 128;
    h1s[j] = fmaxf((float)g[j] - (float)D[k * 128 + j], 0.0f);
    __syncthreads();
    float acc = 0.0f;
    #pragma unroll 8
    for (int i = 0; i < 128; ++i) acc = fmaf(h1s[i], W2[i * 128 + j], acc);
    float p = fmaxf(acc + b2[j], 0.0f) * W3[j];
    #pragma unroll
    for (int m = 1; m < 64; m <<= 1) p += __shfl_xor(p, m, 64);
    if ((j & 63) == 0) red[j >> 6] = p;
    __syncthreads();
    if (j == 0) center[k] = red[0] + red[1] + b3[0];
}

// ----------------------------------------------------------------- pix ----
// (unchanged from v25) 9216 one-wave blocks; raw p stored to dist.
__global__ __launch_bounds__(64)
void pix_kernel(const _Float16* __restrict__ G, const _Float16* __restrict__ D,
                const _Float16* __restrict__ W2f, const int* __restrict__ cent,
                const float* __restrict__ b2, const float* __restrict__ W3,
                float* __restrict__ dist) {
    __shared__ int sjw[CAPX];

    const int l   = threadIdx.x;
    const int lg  = l >> 4;
    const int xi  = l & 15;

    const int bid = blockIdx.x;
    const int r   = row_order(bid / 24);
    const int wx0 = (bid % 24) * 16;

    int nc;
    {
        int base = 0;
        const int2* c2 = (const int2*)cent;
        #pragma unroll
        for (int cch = 0; cch < 4; ++cch) {
            int j = cch * 64 + l;
            int2 cc = c2[j];
            int ty = min(max(cc.x, HALF), HH - HALF) - HALF;
            int tx = min(max(cc.y, HALF), WW - HALF) - HALF;
            bool f = (r >= ty) && (r < ty + 128) &&
                     (tx <= wx0 + 15) && (tx + 127 >= wx0);
            unsigned long long m = __ballot(f);
            int pos = base + __popcll(m & ((1ull << l) - 1ull));
            if (f && pos < CAPX) sjw[pos] = (j << 20) | (ty << 10) | tx;
            base += __popcll(m);
        }
        nc = min(base, CAPX);
    }

    half8 B2w[8][4];
    const half8* W2f8 = (const half8*)W2f;
    #pragma unroll
    for (int n = 0; n < 8; ++n)
        #pragma unroll
        for (int s = 0; s < 4; ++s) B2w[n][s] = W2f8[(n * 4 + s) * 64 + l];

    float b2v[8][4];
    half2v w3pk[8][2];
    #pragma unroll
    for (int n = 0; n < 8; ++n) {
        #pragma unroll
        for (int q = 0; q < 4; ++q) b2v[n][q] = b2[16 * n + 4 * lg + q];
        #pragma unroll
        for (int q = 0; q < 2; ++q)
            w3pk[n][q] = half2v{(_Float16)W3[16 * n + 4 * lg + 2 * q],
                                (_Float16)W3[16 * n + 4 * lg + 2 * q + 1]};
    }

    half8 gA[4];
    {
        const char* Gb = (const char*)G + ((size_t)r * WW + wx0 + xi) * 256 + lg * 16;
        #pragma unroll
        for (int s = 0; s < 4; ++s) gA[s] = *(const half8*)(Gb + s * 64);
    }
    const half8 hz = half8{};

    #pragma unroll 1
    for (int i = 0; i < nc; ++i) {
        int cp = sjw[i];
        int tx = cp & 1023, ty = (cp >> 10) & 1023, j = cp >> 20;

        const char* Dp = (const char*)D + j * 256 + lg * 16;
        half8 hin[4];
        #pragma unroll
        for (int s = 0; s < 4; ++s) {
            half8 dv = *(const half8*)(Dp + s * 64);
            hin[s] = __builtin_elementwise_max(gA[s] - dv, hz);
        }

        float p = 0.0f;
        __builtin_amdgcn_s_setprio(1);
        #pragma unroll
        for (int n = 0; n < 8; ++n) {
            floatx4 acc = floatx4{b2v[n][0], b2v[n][1], b2v[n][2], b2v[n][3]};
            #pragma unroll
            for (int s = 0; s < 4; ++s)
                acc = MFMA16(B2w[n][s], hin[s], acc);
            half2v h0 = __builtin_elementwise_max(pk_f16(acc[0], acc[1]), half2v{});
            half2v h1 = __builtin_elementwise_max(pk_f16(acc[2], acc[3]), half2v{});
            p = __builtin_amdgcn_fdot2(h0, w3pk[n][0], p, false);
            p = __builtin_amdgcn_fdot2(h1, w3pk[n][1], p, false);
        }
        __builtin_amdgcn_s_setprio(0);
        p += __shfl_xor(p, 16, 64);
        p += __shfl_xor(p, 32, 64);

        if (lg == 0) {
            int xcol = wx0 + xi;
            unsigned dx = (unsigned)(xcol - tx);
            if (dx < 128u)
                dist[((size_t)j << 14) + ((r - ty) << 7) + (int)dx] = p;
        }
    }
}

// --------------------------------------------------------------- merge ----
// 2304 blocks of 256. Staging applies +b3/transform; t-loop software-
// pipelined: t+4's Msym gathers issued before t's inner loop.
__global__ __launch_bounds__(256)
void merge_kernel(const float* __restrict__ dist, const int* __restrict__ cent,
                  const float* __restrict__ Msym, const float* __restrict__ center,
                  const float* __restrict__ b3, float* __restrict__ out) {
    __shared__ _Float16 dl[CAPX][64];    // 24 KB
    __shared__ int   sjw[CAPX];
    __shared__ short stx[CAPX];          // static tx per candidate
    __shared__ float smv[4][2][CAPX];    // per-wave double-buffered m values
    __shared__ int   scnt;

    const int tid = threadIdx.x;
    const int l   = tid & 63;
    const int wv  = tid >> 6;
    const int r   = row_order(blockIdx.x / 6);
    const int xt  = blockIdx.x % 6;
    const int px  = xt * 64 + l;
    const float b3s = b3[0];

    if (wv == 0) {
        int base = 0;
        const int2* c2 = (const int2*)cent;
        #pragma unroll
        for (int cch = 0; cch < 4; ++cch) {
            int j = cch * 64 + l;
            int2 cc = c2[j];
            int ty = min(max(cc.x, HALF), HH - HALF) - HALF;
            int tx = min(max(cc.y, HALF), WW - HALF) - HALF;
            bool f = (r >= ty) && (r < ty + 128) &&
                     (tx <= xt * 64 + 63) && (tx + 127 >= xt * 64);
            unsigned long long m = __ballot(f);
            int pos = base + __popcll(m & ((1ull << l) - 1ull));
            if (f && pos < CAPX) sjw[pos] = (j << 20) | (ty << 10) | tx;
            base += __popcll(m);
        }
        if (l == 0) scnt = min(base, CAPX);
    }
    __syncthreads();
    const int nc = scnt;

    // ---- stage dl (+b3, center transform) and static tx ----
    #pragma unroll 1
    for (int j = wv; j < nc; j += 4) {
        int cp = sjw[j];
        int tx = cp & 1023, ty = (cp >> 10) & 1023, jj = cp >> 20;
        stx[j] = (short)tx;
        unsigned dx = (unsigned)(px - tx);
        float v = 0.0f;
        if (dx < 128u) {
            float d = dist[((size_t)jj << 14) + ((r - ty) << 7) + (int)dx] + b3s;
            float bc = center[jj];
            float mm = fmaxf(fmaxf(d, bc), 0.0f);
            float lgv = mm + __logf(__expf(0.0f - mm) + __expf(d - mm) +
                                    __expf(bc - mm));
            v = d + bc - lgv;
        }
        dl[j][l] = (_Float16)v;
    }
    __syncthreads();

    // ---- pipelined t-loop ----
    auto gatherM = [&](int t, float* mv) {
        if (t < nc) {
            const float* mrow = Msym + (sjw[t] >> 20) * NK;
            #pragma unroll
            for (int cch = 0; cch < 3; ++cch) {
                int j2 = cch * 64 + l;
                mv[cch] = (j2 < nc) ? mrow[sjw[j2] >> 20] : 0.0f;
            }
        }
    };

    float mv[3];
    gatherM(wv, mv);
    int cur = 0;
    #pragma unroll 1
    for (int t = wv; t < nc; t += 4) {
        // publish current t's m values (same-wave write->read, no barrier)
        #pragma unroll
        for (int cch = 0; cch < 3; ++cch) {
            int j2 = cch * 64 + l;
            if (j2 < CAPX) smv[wv][cur][j2] = mv[cch];
        }
        gatherM(t + 4, mv);           // next t's gathers fly under inner loop

        int cpt = sjw[t];
        float num = 0.0f, den = 0.0f;
        #pragma unroll 4
        for (int j = 0; j < nc; ++j) {
            float m = smv[wv][cur][j];
            num = fmaf(m, (float)dl[j][l], num);
            unsigned dxj = (unsigned)(px - (int)stx[j]);
            den += (dxj < 128u) ? m : 0.0f;
        }
        unsigned dxk = (unsigned)(px - (cpt & 1023));
        if (dxk < 128u)
            out[((size_t)(cpt >> 20) << 14) + ((r - ((cpt >> 10) & 1023)) << 7) + (int)dxk] =
                num / fmaxf(den, EPSV);
        cur ^= 1;
    }
}

// -------------------------------------------------------------- launch ----
extern "C" void kernel_launch(void* const* d_in, const int* in_sizes, int n_in,
                              void* d_out, int out_size, void* d_ws, size_t ws_size,
                              hipStream_t stream) {
    const float* x     = (const float*)d_in[0];
    const float* sigma = (const float*)d_in[1];
    const float* c     = (const float*)d_in[2];
    const int*   cent  = (const int*)d_in[3];
    const float* M     = (const float*)d_in[4];
    const float* W1    = (const float*)d_in[5];
    const float* b1    = (const float*)d_in[6];
    const float* W2    = (const float*)d_in[7];
    const float* b2    = (const float*)d_in[8];
    const float* W3    = (const float*)d_in[9];
    const float* b3    = (const float*)d_in[10];
    float* out = (float*)d_out;

    float* ws       = (float*)d_ws;
    float* dist     = ws + WS_DIST;
    float* Msym     = ws + WS_MSYM;
    _Float16* W2f   = (_Float16*)(ws + WS_W2F);
    _Float16* D     = (_Float16*)(ws + WS_D);
    float* center   = ws + WS_CENTER;
    _Float16* G     = (_Float16*)(ws + WS_G);

    prepg_kernel<<<832, 256, 0, stream>>>(M, W1, W2, c, b1, x, sigma,
                                          Msym, W2f, D, G);
    center2_kernel<<<256, 128, 0, stream>>>(G, D, W2, b2, W3, b3, cent, center);
    pix_kernel<<<9216, 64, 0, stream>>>(G, D, W2f, cent, b2, W3, dist);
    merge_kernel<<<2304, 256, 0, stream>>>(dist, cent, Msym, center, b3, out);
}

// Round 27
// 267.402 us; speedup vs baseline: 1.4278x; 1.0265x over previous
//
#include <hip/hip_runtime.h>
#include <hip/hip_bf16.h>

// InstanSeg v27 = v26 (274.5us) + merge on matrix cores.
// merge was ~55-60us of pure VALU (t x j masked dot). Now per block:
// XT[128][200] f16 = [dl | has] transposed (200-pad: 16B-aligned rows,
// bank-stride 4 -> free 2-way); per t-tile gather m[t][j] (f16) into
// double-buffered mmt; num&den via MFMA (first op -> D rows convention,
// proven in pix). Gathers for tile t+1 overlap tile t's MFMAs.
// pix/prepg/center2 byte-identical to v26.

#define HH    384
#define WW    384
#define NE    32
#define NK    256
#define HALF  64
#define HWSZ  (HH * WW)
#define EPSV  1e-6f
#define CAPX  192     // per-list candidate cap
#define NCP   200     // padded j-stride (16B-aligned, conflict-free)

typedef _Float16 half8 __attribute__((ext_vector_type(8)));
typedef _Float16 half2v __attribute__((ext_vector_type(2)));
typedef float floatx4 __attribute__((ext_vector_type(4)));

#define MFMA16(a, b, c) __builtin_amdgcn_mfma_f32_16x16x32_f16((a), (b), (c), 0, 0, 0)

__device__ __forceinline__ half2v pk_f16(float a, float b) {
    return __builtin_bit_cast(half2v, __builtin_amdgcn_cvt_pkrtz(a, b));
}

__device__ __forceinline__ int row_order(int ri) {
    return (ri & 1) ? (191 - (ri >> 1)) : (192 + (ri >> 1));
}

// ---- ws layout (float-element offsets) ----
#define WS_DIST   0            // 4,194,304 f32 (16 MB)
#define WS_MSYM   4194304      // 65,536 f32
#define WS_W2F    4259840      // 16,384 f16 = 8,192 f32
#define WS_D      4268032      // 32,768 f16 = 16,384 f32
#define WS_CENTER 4284416      // 256 f32
#define WS_G      5026560      // 18,874,368 f16 = 9,437,184 f32

// ---------------------------------------------------- prep + gfeat fused ----
__global__ void prepg_kernel(const float* __restrict__ M, const float* __restrict__ W1,
                             const float* __restrict__ W2, const float* __restrict__ c,
                             const float* __restrict__ b1,
                             const float* __restrict__ x, const float* __restrict__ sigma,
                             float* __restrict__ Msym, _Float16* __restrict__ W2f,
                             _Float16* __restrict__ D, _Float16* __restrict__ G) {
    const int bid = blockIdx.x;
    const int tid = threadIdx.x;
    if (bid < 256) {
        int idx = bid * 256 + tid;
        {   // Msym
            int i = idx >> 8, j = idx & 255;
            Msym[idx] = (i == j) ? 1.0f : 0.5f * (M[i * NK + j] + M[j * NK + i]);
        }
        if (idx < 2048) {   // W2f B-frags
            int l = idx & 63;
            int col = ((idx >> 8) << 4) + (l & 15);
            int kb = ((idx >> 6) & 3) * 32 + 8 * (l >> 4);
            #pragma unroll
            for (int j = 0; j < 8; ++j)
                W2f[idx * 8 + j] = (_Float16)W2[(kb + j) * 128 + col];
        }
        if (idx < 32768) {  // D[k][h] = W1^T c_k - b1
            int k = idx >> 7, h = idx & 127;
            float s = -b1[h];
            #pragma unroll 8
            for (int e = 0; e < NE; ++e) s = fmaf(c[k * NE + e], W1[e * 128 + h], s);
            D[idx] = (_Float16)s;
        }
    } else {
        int px = (bid - 256) * 256 + tid;
        float f[34];
        #pragma unroll
        for (int e = 0; e < NE; ++e) f[e] = x[e * HWSZ + px];
        f[32] = sigma[px];
        f[33] = sigma[HWSZ + px];
        _Float16* gp = G + (size_t)px * 128;
        #pragma unroll 1
        for (int h0 = 0; h0 < 128; h0 += 8) {
            half8 hv;
            #pragma unroll
            for (int j = 0; j < 8; ++j) {
                float z = 0.0f;
                const float* w1 = W1 + (h0 + j);
                #pragma unroll
                for (int e = 0; e < 34; ++e) z = fmaf(f[e], w1[e * 128], z);
                hv[j] = (_Float16)z;
            }
            *(half8*)(gp + h0) = hv;
        }
    }
}

// -------------------------------------------------------------- center2 ---
__global__ __launch_bounds__(128)
void center2_kernel(const _Float16* __restrict__ G, const _Float16* __restrict__ D,
                    const float* __restrict__ W2, const float* __restrict__ b2,
                    const float* __restrict__ W3, const float* __restrict__ b3,
                    const int* __restrict__ cent, float* __restrict__ center) {
    __shared__ float h1s[128];
    __shared__ float red[2];
    int k = blockIdx.x, j = threadIdx.x;
    int cy0 = cent[2 * k], cx0 = cent[2 * k + 1];
    const _Float16* g = G + ((size_t)cy0 * WW + cx0) * 128;
    h1s[j] = fmaxf((float)g[j] - (float)D[k * 128 + j], 0.0f);
    __syncthreads();
    float acc = 0.0f;
    #pragma unroll 8
    for (int i = 0; i < 128; ++i) acc = fmaf(h1s[i], W2[i * 128 + j], acc);
    float p = fmaxf(acc + b2[j], 0.0f) * W3[j];
    #pragma unroll
    for (int m = 1; m < 64; m <<= 1) p += __shfl_xor(p, m, 64);
    if ((j & 63) == 0) red[j >> 6] = p;
    __syncthreads();
    if (j == 0) center[k] = red[0] + red[1] + b3[0];
}

// ----------------------------------------------------------------- pix ----
// (unchanged from v26) 9216 one-wave blocks; raw p stored to dist.
__global__ __launch_bounds__(64)
void pix_kernel(const _Float16* __restrict__ G, const _Float16* __restrict__ D,
                const _Float16* __restrict__ W2f, const int* __restrict__ cent,
                const float* __restrict__ b2, const float* __restrict__ W3,
                float* __restrict__ dist) {
    __shared__ int sjw[CAPX];

    const int l   = threadIdx.x;
    const int lg  = l >> 4;
    const int xi  = l & 15;

    const int bid = blockIdx.x;
    const int r   = row_order(bid / 24);
    const int wx0 = (bid % 24) * 16;

    int nc;
    {
        int base = 0;
        const int2* c2 = (const int2*)cent;
        #pragma unroll
        for (int cch = 0; cch < 4; ++cch) {
            int j = cch * 64 + l;
            int2 cc = c2[j];
            int ty = min(max(cc.x, HALF), HH - HALF) - HALF;
            int tx = min(max(cc.y, HALF), WW - HALF) - HALF;
            bool f = (r >= ty) && (r < ty + 128) &&
                     (tx <= wx0 + 15) && (tx + 127 >= wx0);
            unsigned long long m = __ballot(f);
            int pos = base + __popcll(m & ((1ull << l) - 1ull));
            if (f && pos < CAPX) sjw[pos] = (j << 20) | (ty << 10) | tx;
            base += __popcll(m);
        }
        nc = min(base, CAPX);
    }

    half8 B2w[8][4];
    const half8* W2f8 = (const half8*)W2f;
    #pragma unroll
    for (int n = 0; n < 8; ++n)
        #pragma unroll
        for (int s = 0; s < 4; ++s) B2w[n][s] = W2f8[(n * 4 + s) * 64 + l];

    float b2v[8][4];
    half2v w3pk[8][2];
    #pragma unroll
    for (int n = 0; n < 8; ++n) {
        #pragma unroll
        for (int q = 0; q < 4; ++q) b2v[n][q] = b2[16 * n + 4 * lg + q];
        #pragma unroll
        for (int q = 0; q < 2; ++q)
            w3pk[n][q] = half2v{(_Float16)W3[16 * n + 4 * lg + 2 * q],
                                (_Float16)W3[16 * n + 4 * lg + 2 * q + 1]};
    }

    half8 gA[4];
    {
        const char* Gb = (const char*)G + ((size_t)r * WW + wx0 + xi) * 256 + lg * 16;
        #pragma unroll
        for (int s = 0; s < 4; ++s) gA[s] = *(const half8*)(Gb + s * 64);
    }
    const half8 hz = half8{};

    #pragma unroll 1
    for (int i = 0; i < nc; ++i) {
        int cp = sjw[i];
        int tx = cp & 1023, ty = (cp >> 10) & 1023, j = cp >> 20;

        const char* Dp = (const char*)D + j * 256 + lg * 16;
        half8 hin[4];
        #pragma unroll
        for (int s = 0; s < 4; ++s) {
            half8 dv = *(const half8*)(Dp + s * 64);
            hin[s] = __builtin_elementwise_max(gA[s] - dv, hz);
        }

        float p = 0.0f;
        __builtin_amdgcn_s_setprio(1);
        #pragma unroll
        for (int n = 0; n < 8; ++n) {
            floatx4 acc = floatx4{b2v[n][0], b2v[n][1], b2v[n][2], b2v[n][3]};
            #pragma unroll
            for (int s = 0; s < 4; ++s)
                acc = MFMA16(B2w[n][s], hin[s], acc);
            half2v h0 = __builtin_elementwise_max(pk_f16(acc[0], acc[1]), half2v{});
            half2v h1 = __builtin_elementwise_max(pk_f16(acc[2], acc[3]), half2v{});
            p = __builtin_amdgcn_fdot2(h0, w3pk[n][0], p, false);
            p = __builtin_amdgcn_fdot2(h1, w3pk[n][1], p, false);
        }
        __builtin_amdgcn_s_setprio(0);
        p += __shfl_xor(p, 16, 64);
        p += __shfl_xor(p, 32, 64);

        if (lg == 0) {
            int xcol = wx0 + xi;
            unsigned dx = (unsigned)(xcol - tx);
            if (dx < 128u)
                dist[((size_t)j << 14) + ((r - ty) << 7) + (int)dx] = p;
        }
    }
}

// --------------------------------------------------------------- merge ----
// 2304 blocks of 256. num/den via MFMA: XT[128][NCP] = [dl | has] (f16,
// transposed); per t-tile m-rows gathered (f16) double-buffered; D-rows=t.
__global__ __launch_bounds__(256)
void merge_kernel(const float* __restrict__ dist, const int* __restrict__ cent,
                  const float* __restrict__ Msym, const float* __restrict__ center,
                  const float* __restrict__ b3, float* __restrict__ out) {
    __shared__ _Float16 XTl[128][NCP];   // 50 KB: rows 0-63 dl, 64-127 has
    __shared__ _Float16 mmt[2][16][NCP]; // 12.5 KB
    __shared__ int   sjw[CAPX];
    __shared__ int   scnt;

    const int tid = threadIdx.x;
    const int l   = tid & 63;
    const int wv  = tid >> 6;
    const int lg  = l >> 4;
    const int xi  = l & 15;
    const int r   = row_order(blockIdx.x / 6);
    const int xt  = blockIdx.x % 6;
    const float b3s = b3[0];

    if (wv == 0) {
        int base = 0;
        const int2* c2 = (const int2*)cent;
        #pragma unroll
        for (int cch = 0; cch < 4; ++cch) {
            int j = cch * 64 + l;
            int2 cc = c2[j];
            int ty = min(max(cc.x, HALF), HH - HALF) - HALF;
            int tx = min(max(cc.y, HALF), WW - HALF) - HALF;
            bool f = (r >= ty) && (r < ty + 128) &&
                     (tx <= xt * 64 + 63) && (tx + 127 >= xt * 64);
            unsigned long long m = __ballot(f);
            int pos = base + __popcll(m & ((1ull << l) - 1ull));
            if (f && pos < CAPX) sjw[pos] = (j << 20) | (ty << 10) | tx;
            base += __popcll(m);
        }
        if (l == 0) scnt = min(base, CAPX);
    }
    __syncthreads();
    const int nc  = scnt;
    if (nc == 0) return;                         // no window covers this span
    const int ncw = (nc + 31) & ~31;             // k-dim padded to 32
    const int px  = xt * 64 + l;

    // ---- stage XT: dl (transform applied) and has, transposed ----
    #pragma unroll 1
    for (int j = wv; j < nc; j += 4) {
        int cp = sjw[j];
        int tx = cp & 1023, ty = (cp >> 10) & 1023, jj = cp >> 20;
        unsigned dx = (unsigned)(px - tx);
        float v = 0.0f, hv = 0.0f;
        if (dx < 128u) {
            float d = dist[((size_t)jj << 14) + ((r - ty) << 7) + (int)dx] + b3s;
            float bc = center[jj];
            float mm = fmaxf(fmaxf(d, bc), 0.0f);
            float lgv = mm + __logf(__expf(0.0f - mm) + __expf(d - mm) +
                                    __expf(bc - mm));
            v = d + bc - lgv;
            hv = 1.0f;
        }
        XTl[l][j]      = (_Float16)v;
        XTl[64 + l][j] = (_Float16)hv;
    }
    #pragma unroll 1
    for (int j = nc + wv; j < ncw; j += 4) {     // zero-pad k columns
        XTl[l][j]      = (_Float16)0.0f;
        XTl[64 + l][j] = (_Float16)0.0f;
    }

    const int ntt = (nc + 15) >> 4;              // t-tiles
    const int ks  = ncw >> 5;                    // k-steps

    // gather m rows (f16) for t-tile tt into mmt[buf]
    auto gatherM = [&](int tt, int buf) {
        if (tt >= ntt) return;
        int tl = tid >> 4;                       // 16 threads per t-row
        int tg = tt * 16 + tl;
        int kt = (tg < nc) ? (sjw[tg] >> 20) : -1;
        const float* mrow = Msym + kt * NK;
        for (int j = tid & 15; j < ncw; j += 16) {
            float mv = 0.0f;
            if (kt >= 0 && j < nc) mv = mrow[sjw[j] >> 20];
            mmt[buf][tl][j] = (_Float16)mv;
        }
    };

    gatherM(0, 0);
    __syncthreads();                             // XT + mmt[0] ready

    #pragma unroll 1
    for (int tt = 0; tt < ntt; ++tt) {
        int buf = tt & 1;
        gatherM(tt + 1, buf ^ 1);                // overlap next gathers

        floatx4 accN = floatx4{0.0f, 0.0f, 0.0f, 0.0f};
        floatx4 accD = accN;
        #pragma unroll 1
        for (int s = 0; s < ks; ++s) {
            half8 a  = *(const half8*)&mmt[buf][xi][32 * s + 8 * lg];
            half8 bN = *(const half8*)&XTl[16 * wv + xi][32 * s + 8 * lg];
            half8 bD = *(const half8*)&XTl[64 + 16 * wv + xi][32 * s + 8 * lg];
            accN = MFMA16(a, bN, accN);          // D[row=t, col=px-tile wv]
            accD = MFMA16(a, bD, accD);
        }

        #pragma unroll
        for (int q = 0; q < 4; ++q) {
            int tg = tt * 16 + 4 * lg + q;
            if (tg < nc) {
                int cp = sjw[tg];
                int tx = cp & 1023, ty = (cp >> 10) & 1023, kt = cp >> 20;
                int gp = xt * 64 + 16 * wv + xi;
                unsigned dx = (unsigned)(gp - tx);
                if (dx < 128u)
                    out[((size_t)kt << 14) + ((r - ty) << 7) + (int)dx] =
                        accN[q] / fmaxf(accD[q], EPSV);
            }
        }
        __syncthreads();                         // mmt[buf^1] ready / reuse
    }
}

// -------------------------------------------------------------- launch ----
extern "C" void kernel_launch(void* const* d_in, const int* in_sizes, int n_in,
                              void* d_out, int out_size, void* d_ws, size_t ws_size,
                              hipStream_t stream) {
    const float* x     = (const float*)d_in[0];
    const float* sigma = (const float*)d_in[1];
    const float* c     = (const float*)d_in[2];
    const int*   cent  = (const int*)d_in[3];
    const float* M     = (const float*)d_in[4];
    const float* W1    = (const float*)d_in[5];
    const float* b1    = (const float*)d_in[6];
    const float* W2    = (const float*)d_in[7];
    const float* b2    = (const float*)d_in[8];
    const float* W3    = (const float*)d_in[9];
    const float* b3    = (const float*)d_in[10];
    float* out = (float*)d_out;

    float* ws       = (float*)d_ws;
    float* dist     = ws + WS_DIST;
    float* Msym     = ws + WS_MSYM;
    _Float16* W2f   = (_Float16*)(ws + WS_W2F);
    _Float16* D     = (_Float16*)(ws + WS_D);
    float* center   = ws + WS_CENTER;
    _Float16* G     = (_Float16*)(ws + WS_G);

    prepg_kernel<<<832, 256, 0, stream>>>(M, W1, W2, c, b1, x, sigma,
                                          Msym, W2f, D, G);
    center2_kernel<<<256, 128, 0, stream>>>(G, D, W2, b2, W3, b3, cent, center);
    pix_kernel<<<9216, 64, 0, stream>>>(G, D, W2f, cent, b2, W3, dist);
    merge_kernel<<<2304, 256, 0, stream>>>(dist, cent, Msym, center, b3, out);
}